// Round 16
// baseline (390.894 us; speedup 1.0000x reference)
//
#include <hip/hip_runtime.h>

#define TT 8192          // B*S tokens
#define DD 1024          // model dim
#define HHH 2048         // hidden dim
#define EE 8             // experts
#define MUf 0.7f
#define GAMMAf 1.0f
#define LNEPS 1e-5f

typedef __bf16 bf16x8 __attribute__((ext_vector_type(8)));
typedef float floatx4 __attribute__((ext_vector_type(4)));

__device__ __forceinline__ unsigned short f2bf(float f) {
  unsigned u = __float_as_uint(f);
  u += 0x7FFFu + ((u >> 16) & 1u);          // round-to-nearest-even
  return (unsigned short)(u >> 16);
}
__device__ __forceinline__ float bf2f(unsigned short u) {
  return __uint_as_float(((unsigned)u) << 16);
}
__device__ __forceinline__ void load_lds16(const void* g, void* l) {
  __builtin_amdgcn_global_load_lds(
      (__attribute__((address_space(1))) void*)g,
      (__attribute__((address_space(3))) void*)l,
      16, 0, 0);
}

// ------- fused x->bf16 convert + router (each block = exactly 2 token rows) -------
__global__ __launch_bounds__(256) void cvt_router_kernel(
    const float* __restrict__ x, const float* __restrict__ Wg, const float* __restrict__ bg,
    unsigned short* __restrict__ xb,
    int* __restrict__ pair_e, float* __restrict__ pair_w) {
  int tid = threadIdx.x;
  size_t gi = (size_t)blockIdx.x * 2048 + (size_t)tid * 8;
  const float4* s = (const float4*)(x + gi);
  float4 a = s[0], b = s[1];
  unsigned r0 = f2bf(a.x) | ((unsigned)f2bf(a.y) << 16);
  unsigned r1 = f2bf(a.z) | ((unsigned)f2bf(a.w) << 16);
  unsigned r2 = f2bf(b.x) | ((unsigned)f2bf(b.y) << 16);
  unsigned r3 = f2bf(b.z) | ((unsigned)f2bf(b.w) << 16);
  ((uint4*)xb)[blockIdx.x * 256 + tid] = make_uint4(r0, r1, r2, r3);

  float xa[8] = {a.x, a.y, a.z, a.w, b.x, b.y, b.z, b.w};
  int d0 = (tid & 127) * 8;
  const float* wbase = Wg + (size_t)d0 * EE;
  float acc[EE];
#pragma unroll
  for (int e = 0; e < EE; ++e) acc[e] = 0.f;
#pragma unroll
  for (int i = 0; i < 8; ++i) {
    float4 w0 = *(const float4*)(wbase + i * EE);
    float4 w1 = *(const float4*)(wbase + i * EE + 4);
    acc[0] += xa[i] * w0.x; acc[1] += xa[i] * w0.y;
    acc[2] += xa[i] * w0.z; acc[3] += xa[i] * w0.w;
    acc[4] += xa[i] * w1.x; acc[5] += xa[i] * w1.y;
    acc[6] += xa[i] * w1.z; acc[7] += xa[i] * w1.w;
  }
#pragma unroll
  for (int e = 0; e < EE; ++e) {
#pragma unroll
    for (int off = 32; off > 0; off >>= 1) acc[e] += __shfl_xor(acc[e], off);
  }
  __shared__ float rs[4][EE];
  int wv = tid >> 6;
  if ((tid & 63) == 0) {
#pragma unroll
    for (int e = 0; e < EE; ++e) rs[wv][e] = acc[e];
  }
  __syncthreads();
  if ((tid & 127) == 0) {
    int half = tid >> 7;
    int t = blockIdx.x * 2 + half;
    float v[EE];
#pragma unroll
    for (int e = 0; e < EE; ++e) v[e] = rs[2 * half][e] + rs[2 * half + 1][e] + bg[e];
    int i0 = 0;
#pragma unroll
    for (int e = 1; e < EE; ++e) if (v[e] > v[i0]) i0 = e;      // ties -> lowest idx
    int i1 = (i0 == 0) ? 1 : 0;
#pragma unroll
    for (int e = 0; e < EE; ++e) if (e != i0 && v[e] > v[i1]) i1 = e;
    float w1e = __expf(v[i1] - v[i0]);
    float inv = 1.f / (1.f + w1e);
    pair_e[2 * t] = i0;     pair_w[2 * t] = inv;
    pair_e[2 * t + 1] = i1; pair_w[2 * t + 1] = w1e * inv;
  }
}

// ------- LDS-aggregated histogram -------
__global__ __launch_bounds__(256) void count_kernel(const int* __restrict__ pair_e,
                                                    int* __restrict__ counts) {
  __shared__ int lh[EE];
  int tid = threadIdx.x;
  if (tid < EE) lh[tid] = 0;
  __syncthreads();
  int p = blockIdx.x * 256 + tid;
  atomicAdd(&lh[pair_e[p]], 1);
  __syncthreads();
  if (tid < EE) atomicAdd(&counts[tid], lh[tid]);
}

__global__ void prefix_kernel(const int* __restrict__ counts, int* __restrict__ offs,
                              int* __restrict__ cursor) {
  if (threadIdx.x == 0) {
    int s = 0;
    for (int e = 0; e < EE; ++e) { offs[e] = s; cursor[e] = s; s += counts[e]; }
    offs[EE] = s;
  }
}

// ------- chunk-reserving scatter -------
__global__ __launch_bounds__(256) void scatter_kernel(const int* __restrict__ pair_e,
                                                      int* __restrict__ cursor,
                                                      int* __restrict__ pair_rows) {
  __shared__ int lh[EE];
  __shared__ int lb[EE];
  int tid = threadIdx.x;
  if (tid < EE) lh[tid] = 0;
  __syncthreads();
  int p = blockIdx.x * 256 + tid;
  int e = pair_e[p];
  int r = atomicAdd(&lh[e], 1);
  __syncthreads();
  if (tid < EE) lb[tid] = atomicAdd(&cursor[tid], lh[tid]);
  __syncthreads();
  pair_rows[lb[e] + r] = p;
}

// ---------------- per-expert transpose + cvt: [R][C] f32 -> [C][R] bf16 ----------------
__global__ __launch_bounds__(256) void transpose_cvt_kernel(const float* __restrict__ in,
                                                            unsigned short* __restrict__ out,
                                                            int R, int C) {
  __shared__ float tile[32][33];
  int e = blockIdx.z;
  const float* src = in + (size_t)e * R * C;
  unsigned short* dst = out + (size_t)e * R * C;
  int c0 = blockIdx.x * 32, r0 = blockIdx.y * 32;
  int tx = threadIdx.x, ty = threadIdx.y;
#pragma unroll
  for (int i = 0; i < 32; i += 8)
    tile[ty + i][tx] = src[(size_t)(r0 + ty + i) * C + (c0 + tx)];
  __syncthreads();
#pragma unroll
  for (int i = 0; i < 32; i += 8)
    dst[(size_t)(c0 + ty + i) * R + (r0 + tx)] = f2bf(tile[tx][ty + i]);
}

// ------- grouped GEMM, 128x128 tile, BK=32, 4-slab ring, SINGLE barrier + vmcnt(4) -------
// Expert->XCD pinning: block d -> expert (d&7), tile (d>>3) (flat grid, round-robin %8).
// Safety of the single barrier: stage at iter j targets slot (j+2)&3, last read at iter
// j-2; passing barrier j implies all waves completed iter j-1 (and hence j-2's reads).
// vmcnt(4) at top of iter j: 8 loads outstanding (tiles j, j+1) -> oldest 4 (tile j)
// landed, tile j+1 stays in flight across the barrier. Tail iters drain with vmcnt(0).
// MODE 0: A = xb gathered via pair_rows, epilogue relu -> h[sorted_pos]
// MODE 1: A = h (sorted rows direct),    epilogue gate-scale -> pairout[pair]
template <int MODE>
__global__ __launch_bounds__(256, 2) void moe_gemm_kernel(
    const unsigned short* __restrict__ Amat, const unsigned short* __restrict__ Bmat,
    const float* __restrict__ bias, const int* __restrict__ offsets,
    const int* __restrict__ pair_rows, const float* __restrict__ pair_w,
    unsigned short* __restrict__ Out, int Kd, int Nd, int nxlog) {
  int d = blockIdx.x;
  int e = d & 7;                               // expert == XCD (round-robin %8)
  int lin = d >> 3;
  int mt = lin >> nxlog;                       // m-tile
  int n0 = (lin & ((1 << nxlog) - 1)) << 7;    // n-tile * 128
  int off = offsets[e];
  int cnt = offsets[e + 1] - off;
  if (mt * 128 >= cnt) return;
  int tid = threadIdx.x;
  int lane = tid & 63, wid = tid >> 6;

  __shared__ unsigned short As[4][128 * 32];   // 4 x 8 KB
  __shared__ unsigned short Bs[4][128 * 32];   // 4 x 8 KB  (64 KB total -> 2 blocks/CU)

  const unsigned short* Bex = Bmat + (size_t)e * Nd * Kd;

  // Staging: thread -> row tid>>2 (P*64 offset), 16B chunk tid&3; source chunk XOR row&3.
  int csw = (((tid & 3) ^ ((tid >> 2) & 3)) * 8);
  const unsigned short* aptr[2];
  const unsigned short* bptr[2];
#pragma unroll
  for (int P = 0; P < 2; ++P) {
    int row = P * 64 + (tid >> 2);
    int sa = mt * 128 + row;
    if (sa >= cnt) sa = cnt - 1;              // clamp (dup loads; masked at C-write)
    int gr = (MODE == 0) ? (pair_rows[off + sa] >> 1) : (off + sa);
    aptr[P] = Amat + (size_t)gr * Kd + csw;
    bptr[P] = Bex + (size_t)(n0 + row) * Kd + csw;
  }

  int wm = (wid >> 1) * 64, wn = (wid & 1) * 64;
  int lr = lane & 15;
  int t4 = lane >> 4;                         // k-chunk 0..3
  int lka = ((t4 ^ (lr & 3)) * 8);            // swizzled read element offset

  floatx4 acc[4][4];
#pragma unroll
  for (int m = 0; m < 4; ++m)
#pragma unroll
    for (int n = 0; n < 4; ++n) acc[m][n] = (floatx4){0.f, 0.f, 0.f, 0.f};

  int NT = Kd >> 5;
  // prologue: stage K-tiles 0 and 1 into ring slots 0,1 (dest linear: base + tid*16B)
#pragma unroll
  for (int P = 0; P < 2; ++P) {
    load_lds16(aptr[P], &As[0][P * 2048] + tid * 8);
    load_lds16(bptr[P], &Bs[0][P * 2048] + tid * 8);
  }
#pragma unroll
  for (int P = 0; P < 2; ++P) {
    load_lds16(aptr[P] + 32, &As[1][P * 2048] + tid * 8);
    load_lds16(bptr[P] + 32, &Bs[1][P * 2048] + tid * 8);
  }

  for (int kt = 0; kt < NT; ++kt) {
    if (kt + 1 < NT) {
      asm volatile("s_waitcnt vmcnt(4)" ::: "memory");  // tile kt landed; kt+1 in flight
    } else {
      asm volatile("s_waitcnt vmcnt(0)" ::: "memory");  // last tile: drain
    }
    __builtin_amdgcn_s_barrier();             // all waves done with iter kt-1 (=> kt-2 reads)
    __builtin_amdgcn_sched_barrier(0);        // pin stage-issue after the barrier
    int pf = kt + 2;
    if (pf < NT) {                            // stage 2 tiles ahead into slot (kt+2)&3
      int ko = pf * 32;
      int pb = pf & 3;
#pragma unroll
      for (int P = 0; P < 2; ++P) {
        load_lds16(aptr[P] + ko, &As[pb][P * 2048] + tid * 8);
        load_lds16(bptr[P] + ko, &Bs[pb][P * 2048] + tid * 8);
      }
    }
    int b = kt & 3;
    bf16x8 af[4], bfr[4];
#pragma unroll
    for (int m = 0; m < 4; ++m)
      af[m] = *(const bf16x8*)(&As[b][(wm + m * 16 + lr) * 32 + lka]);
#pragma unroll
    for (int n = 0; n < 4; ++n)
      bfr[n] = *(const bf16x8*)(&Bs[b][(wn + n * 16 + lr) * 32 + lka]);
    __builtin_amdgcn_s_setprio(1);
#pragma unroll
    for (int m = 0; m < 4; ++m)
#pragma unroll
      for (int n = 0; n < 4; ++n)
        acc[m][n] = __builtin_amdgcn_mfma_f32_16x16x32_bf16(af[m], bfr[n], acc[m][n], 0, 0, 0);
    __builtin_amdgcn_s_setprio(0);
  }

  int rem = cnt - mt * 128;
  if (rem > 128) rem = 128;
#pragma unroll
  for (int m = 0; m < 4; ++m) {
#pragma unroll
    for (int j = 0; j < 4; ++j) {
      int lrr = wm + m * 16 + ((lane >> 4) << 2) + j;   // C/D: col=lane&15, row=(lane>>4)*4+j
      if (lrr < rem) {
        int s = mt * 128 + lrr;
        size_t orow;
        float scale = 1.f;
        if (MODE == 0) {
          orow = (size_t)(off + s) * Nd;
        } else {
          int p = pair_rows[off + s];
          orow = (size_t)p * Nd;
          scale = pair_w[p];
        }
#pragma unroll
        for (int n = 0; n < 4; ++n) {
          int col = n0 + wn + n * 16 + lr;
          float v = acc[m][n][j] + bias[e * Nd + col];
          if (MODE == 0) v = fmaxf(v, 0.f);
          else v *= scale;
          Out[orow + col] = f2bf(v);
        }
      }
    }
  }
}

// ---------------- fused epilogue: sum pairs, momentum, residual, LayerNorm ----------------
__global__ __launch_bounds__(256) void final_kernel(
    const float* __restrict__ x, const float* __restrict__ mom,
    const unsigned short* __restrict__ pairout, const float* __restrict__ ln_g,
    const float* __restrict__ ln_b, float* __restrict__ outp, float* __restrict__ nmp) {
  int t = blockIdx.x, tid = threadIdx.x;
  int d0 = tid * 4;
  size_t rowoff = (size_t)t * DD;
  const unsigned short* p0 = pairout + (size_t)(2 * t) * DD;
  const unsigned short* p1 = p0 + DD;
  float4 xv = *(const float4*)(x + rowoff + d0);
  float4 mv = *(const float4*)(mom + rowoff + d0);
  ushort4 u0 = *(const ushort4*)(p0 + d0);
  ushort4 u1 = *(const ushort4*)(p1 + d0);
  float eo[4] = {bf2f(u0.x) + bf2f(u1.x), bf2f(u0.y) + bf2f(u1.y),
                 bf2f(u0.z) + bf2f(u1.z), bf2f(u0.w) + bf2f(u1.w)};
  float xa[4] = {xv.x, xv.y, xv.z, xv.w};
  float ma[4] = {mv.x, mv.y, mv.z, mv.w};
  float o[4], nm[4];
  float s1 = 0.f, s2 = 0.f;
#pragma unroll
  for (int j = 0; j < 4; ++j) {
    nm[j] = MUf * ma[j] - eo[j];
    o[j] = xa[j] + GAMMAf * nm[j];
    s1 += o[j];
    s2 += o[j] * o[j];
  }
  *(float4*)(nmp + rowoff + d0) = make_float4(nm[0], nm[1], nm[2], nm[3]);
#pragma unroll
  for (int off = 32; off > 0; off >>= 1) {
    s1 += __shfl_xor(s1, off);
    s2 += __shfl_xor(s2, off);
  }
  __shared__ float rs[8];
  int wid = tid >> 6, lane = tid & 63;
  if (lane == 0) { rs[wid] = s1; rs[4 + wid] = s2; }
  __syncthreads();
  s1 = rs[0] + rs[1] + rs[2] + rs[3];
  s2 = rs[4] + rs[5] + rs[6] + rs[7];
  float mean = s1 * (1.f / DD);
  float var = s2 * (1.f / DD) - mean * mean;
  float rstd = rsqrtf(var + LNEPS);
  float4 g = *(const float4*)(ln_g + d0);
  float4 bb = *(const float4*)(ln_b + d0);
  float ga[4] = {g.x, g.y, g.z, g.w}, ba[4] = {bb.x, bb.y, bb.z, bb.w};
  float res[4];
#pragma unroll
  for (int j = 0; j < 4; ++j) res[j] = (o[j] - mean) * rstd * ga[j] + ba[j];
  *(float4*)(outp + rowoff + d0) = make_float4(res[0], res[1], res[2], res[3]);
}

extern "C" void kernel_launch(void* const* d_in, const int* in_sizes, int n_in,
                              void* d_out, int out_size, void* d_ws, size_t ws_size,
                              hipStream_t stream) {
  const float* x   = (const float*)d_in[0];
  const float* mom = (const float*)d_in[1];
  const float* Wg  = (const float*)d_in[2];
  const float* bg  = (const float*)d_in[3];
  const float* W1  = (const float*)d_in[4];
  const float* b1  = (const float*)d_in[5];
  const float* W2  = (const float*)d_in[6];
  const float* b2  = (const float*)d_in[7];
  const float* lng = (const float*)d_in[8];
  const float* lnb = (const float*)d_in[9];
  (void)in_sizes; (void)n_in; (void)out_size; (void)ws_size;
  float* outp = (float*)d_out;
  float* nmp  = outp + (size_t)TT * DD;

  char* base = (char*)d_ws;
  size_t off = 0;
  auto carve = [&](size_t bytes) {
    void* p = base + off;
    off += (bytes + 255) & ~(size_t)255;
    return p;
  };
  unsigned short* xb   = (unsigned short*)carve((size_t)TT * DD * 2);        // 16 MB
  unsigned short* w1t  = (unsigned short*)carve((size_t)EE * HHH * DD * 2);  // 32 MB  [E][H][D]
  unsigned short* w2t  = (unsigned short*)carve((size_t)EE * DD * HHH * 2);  // 32 MB  [E][D][H]
  unsigned short* hbuf = (unsigned short*)carve((size_t)2 * TT * HHH * 2);   // 64 MB
  unsigned short* pout = (unsigned short*)carve((size_t)2 * TT * DD * 2);    // 32 MB
  int*   pair_e    = (int*)carve((size_t)2 * TT * 4);
  float* pair_w    = (float*)carve((size_t)2 * TT * 4);
  int*   pair_rows = (int*)carve((size_t)2 * TT * 4);
  int*   counts    = (int*)carve(256);
  int*   offs      = (int*)carve(256);
  int*   cursor    = (int*)carve(256);

  hipMemsetAsync(counts, 0, EE * sizeof(int), stream);
  cvt_router_kernel<<<TT / 2, 256, 0, stream>>>(x, Wg, bg, xb, pair_e, pair_w);
  count_kernel<<<(2 * TT) / 256, 256, 0, stream>>>(pair_e, counts);
  prefix_kernel<<<1, 64, 0, stream>>>(counts, offs, cursor);
  scatter_kernel<<<(2 * TT) / 256, 256, 0, stream>>>(pair_e, cursor, pair_rows);
  transpose_cvt_kernel<<<dim3(HHH / 32, DD / 32, EE), dim3(32, 8, 1), 0, stream>>>(W1, w1t, DD, HHH);
  transpose_cvt_kernel<<<dim3(DD / 32, HHH / 32, EE), dim3(32, 8, 1), 0, stream>>>(W2, w2t, HHH, DD);
  // flat grids: 8 experts x (NX n-tiles x 128 m-tiles); expert = blockIdx.x & 7
  moe_gemm_kernel<0><<<EE * (HHH / 128) * 128, 256, 0, stream>>>(
      xb, w1t, b1, offs, pair_rows, pair_w, hbuf, DD, HHH, 4);
  moe_gemm_kernel<1><<<EE * (DD / 128) * 128, 256, 0, stream>>>(
      hbuf, w2t, b2, offs, pair_rows, pair_w, pout, HHH, DD, 3);
  final_kernel<<<TT, 256, 0, stream>>>(x, mom, pout, lng, lnb, outp, nmp);
}

// Round 17
// 320.617 us; speedup vs baseline: 1.2192x; 1.2192x over previous
//
#include <hip/hip_runtime.h>

#define TT 8192          // B*S tokens
#define DD 1024          // model dim
#define HHH 2048         // hidden dim
#define EE 8             // experts
#define MUf 0.7f
#define GAMMAf 1.0f
#define LNEPS 1e-5f

typedef __bf16 bf16x8 __attribute__((ext_vector_type(8)));
typedef float floatx4 __attribute__((ext_vector_type(4)));

__device__ __forceinline__ unsigned short f2bf(float f) {
  unsigned u = __float_as_uint(f);
  u += 0x7FFFu + ((u >> 16) & 1u);          // round-to-nearest-even
  return (unsigned short)(u >> 16);
}
__device__ __forceinline__ float bf2f(unsigned short u) {
  return __uint_as_float(((unsigned)u) << 16);
}
__device__ __forceinline__ void load_lds16(const void* g, void* l) {
  __builtin_amdgcn_global_load_lds(
      (__attribute__((address_space(1))) void*)g,
      (__attribute__((address_space(3))) void*)l,
      16, 0, 0);
}

// ------- fused x->bf16 convert + router (each block = exactly 2 token rows) -------
__global__ __launch_bounds__(256) void cvt_router_kernel(
    const float* __restrict__ x, const float* __restrict__ Wg, const float* __restrict__ bg,
    unsigned short* __restrict__ xb,
    int* __restrict__ pair_e, float* __restrict__ pair_w) {
  int tid = threadIdx.x;
  size_t gi = (size_t)blockIdx.x * 2048 + (size_t)tid * 8;
  const float4* s = (const float4*)(x + gi);
  float4 a = s[0], b = s[1];
  unsigned r0 = f2bf(a.x) | ((unsigned)f2bf(a.y) << 16);
  unsigned r1 = f2bf(a.z) | ((unsigned)f2bf(a.w) << 16);
  unsigned r2 = f2bf(b.x) | ((unsigned)f2bf(b.y) << 16);
  unsigned r3 = f2bf(b.z) | ((unsigned)f2bf(b.w) << 16);
  ((uint4*)xb)[blockIdx.x * 256 + tid] = make_uint4(r0, r1, r2, r3);

  float xa[8] = {a.x, a.y, a.z, a.w, b.x, b.y, b.z, b.w};
  int d0 = (tid & 127) * 8;
  const float* wbase = Wg + (size_t)d0 * EE;
  float acc[EE];
#pragma unroll
  for (int e = 0; e < EE; ++e) acc[e] = 0.f;
#pragma unroll
  for (int i = 0; i < 8; ++i) {
    float4 w0 = *(const float4*)(wbase + i * EE);
    float4 w1 = *(const float4*)(wbase + i * EE + 4);
    acc[0] += xa[i] * w0.x; acc[1] += xa[i] * w0.y;
    acc[2] += xa[i] * w0.z; acc[3] += xa[i] * w0.w;
    acc[4] += xa[i] * w1.x; acc[5] += xa[i] * w1.y;
    acc[6] += xa[i] * w1.z; acc[7] += xa[i] * w1.w;
  }
#pragma unroll
  for (int e = 0; e < EE; ++e) {
#pragma unroll
    for (int off = 32; off > 0; off >>= 1) acc[e] += __shfl_xor(acc[e], off);
  }
  __shared__ float rs[4][EE];
  int wv = tid >> 6;
  if ((tid & 63) == 0) {
#pragma unroll
    for (int e = 0; e < EE; ++e) rs[wv][e] = acc[e];
  }
  __syncthreads();
  if ((tid & 127) == 0) {
    int half = tid >> 7;
    int t = blockIdx.x * 2 + half;
    float v[EE];
#pragma unroll
    for (int e = 0; e < EE; ++e) v[e] = rs[2 * half][e] + rs[2 * half + 1][e] + bg[e];
    int i0 = 0;
#pragma unroll
    for (int e = 1; e < EE; ++e) if (v[e] > v[i0]) i0 = e;      // ties -> lowest idx
    int i1 = (i0 == 0) ? 1 : 0;
#pragma unroll
    for (int e = 0; e < EE; ++e) if (e != i0 && v[e] > v[i1]) i1 = e;
    float w1e = __expf(v[i1] - v[i0]);
    float inv = 1.f / (1.f + w1e);
    pair_e[2 * t] = i0;     pair_w[2 * t] = inv;
    pair_e[2 * t + 1] = i1; pair_w[2 * t + 1] = w1e * inv;
  }
}

// ------- LDS-aggregated histogram -------
__global__ __launch_bounds__(256) void count_kernel(const int* __restrict__ pair_e,
                                                    int* __restrict__ counts) {
  __shared__ int lh[EE];
  int tid = threadIdx.x;
  if (tid < EE) lh[tid] = 0;
  __syncthreads();
  int p = blockIdx.x * 256 + tid;
  atomicAdd(&lh[pair_e[p]], 1);
  __syncthreads();
  if (tid < EE) atomicAdd(&counts[tid], lh[tid]);
}

__global__ void prefix_kernel(const int* __restrict__ counts, int* __restrict__ offs,
                              int* __restrict__ cursor) {
  if (threadIdx.x == 0) {
    int s = 0;
    for (int e = 0; e < EE; ++e) { offs[e] = s; cursor[e] = s; s += counts[e]; }
    offs[EE] = s;
  }
}

// ------- chunk-reserving scatter -------
__global__ __launch_bounds__(256) void scatter_kernel(const int* __restrict__ pair_e,
                                                      int* __restrict__ cursor,
                                                      int* __restrict__ pair_rows) {
  __shared__ int lh[EE];
  __shared__ int lb[EE];
  int tid = threadIdx.x;
  if (tid < EE) lh[tid] = 0;
  __syncthreads();
  int p = blockIdx.x * 256 + tid;
  int e = pair_e[p];
  int r = atomicAdd(&lh[e], 1);
  __syncthreads();
  if (tid < EE) lb[tid] = atomicAdd(&cursor[tid], lh[tid]);
  __syncthreads();
  pair_rows[lb[e] + r] = p;
}

// ---- per-expert transpose+cvt, 64x64 tiles, float4 loads / ushort4 stores ----
__global__ __launch_bounds__(256) void transpose_cvt_kernel(const float* __restrict__ in,
                                                            unsigned short* __restrict__ out,
                                                            int R, int C) {
  __shared__ float tile[64][65];
  int e = blockIdx.z;
  const float* src = in + (size_t)e * R * C;
  unsigned short* dst = out + (size_t)e * R * C;
  int c0 = blockIdx.x * 64, r0 = blockIdx.y * 64;
  int t = threadIdx.x;
  int q = t & 15, r = t >> 4;
#pragma unroll
  for (int i = 0; i < 4; ++i) {
    int rr = r + 16 * i;
    float4 v = *(const float4*)(src + (size_t)(r0 + rr) * C + c0 + q * 4);
    tile[rr][q * 4 + 0] = v.x; tile[rr][q * 4 + 1] = v.y;
    tile[rr][q * 4 + 2] = v.z; tile[rr][q * 4 + 3] = v.w;
  }
  __syncthreads();
  int g = t & 15, cc = t >> 4;
#pragma unroll
  for (int i = 0; i < 4; ++i) {
    int c = cc + 16 * i;
    ushort4 o;
    o.x = f2bf(tile[g * 4 + 0][c]);
    o.y = f2bf(tile[g * 4 + 1][c]);
    o.z = f2bf(tile[g * 4 + 2][c]);
    o.w = f2bf(tile[g * 4 + 3][c]);
    *(ushort4*)(dst + (size_t)(c0 + c) * R + r0 + g * 4) = o;
  }
}

// ------- grouped GEMM, 128x128 tile, BK=32, 3-slab ring, SINGLE barrier + vmcnt(4) -------
// Expert->XCD pinning: block d -> expert (d&7), tile (d>>3) (flat grid, round-robin %8).
// Single-barrier safety with 3 slabs, distance-2 prefetch: the stage at iter j targets
// slot (j+2)%3 == (j-1)%3, read during iter j-1. Every wave's iter-(j-1) ds_reads complete
// before it reaches barrier j (program order + lgkmcnt before MFMA), and the stage is
// issued after barrier j (sched_barrier pins it) -> no read/write race. LDS stays 48 KB
// -> 3 blocks/CU (round-14's 64 KB/2-block regression avoided).
// vmcnt(4) at top of iter j: outstanding = tiles j, j+1 (4 loads each); oldest 4 (tile j)
// landed, tile j+1 stays in flight across the barrier. Tail iters drain with vmcnt(0).
// MODE 0: A = xb gathered via pair_rows, epilogue relu -> h[sorted_pos]
// MODE 1: A = h (sorted rows direct),    epilogue gate-scale -> pairout[pair]
template <int MODE>
__global__ __launch_bounds__(256, 3) void moe_gemm_kernel(
    const unsigned short* __restrict__ Amat, const unsigned short* __restrict__ Bmat,
    const float* __restrict__ bias, const int* __restrict__ offsets,
    const int* __restrict__ pair_rows, const float* __restrict__ pair_w,
    unsigned short* __restrict__ Out, int Kd, int Nd, int nxlog) {
  int d = blockIdx.x;
  int e = d & 7;                               // expert == XCD (round-robin %8)
  int lin = d >> 3;
  int mt = lin >> nxlog;                       // m-tile
  int n0 = (lin & ((1 << nxlog) - 1)) << 7;    // n-tile * 128
  int off = offsets[e];
  int cnt = offsets[e + 1] - off;
  if (mt * 128 >= cnt) return;
  int tid = threadIdx.x;
  int lane = tid & 63, wid = tid >> 6;

  __shared__ unsigned short As[3][128 * 32];   // 3 x 8 KB
  __shared__ unsigned short Bs[3][128 * 32];   // 3 x 8 KB  (48 KB total -> 3 blocks/CU)

  const unsigned short* Bex = Bmat + (size_t)e * Nd * Kd;

  // Staging: thread -> row tid>>2 (P*64 offset), 16B chunk tid&3; source chunk XOR row&3.
  int csw = (((tid & 3) ^ ((tid >> 2) & 3)) * 8);
  const unsigned short* aptr[2];
  const unsigned short* bptr[2];
#pragma unroll
  for (int P = 0; P < 2; ++P) {
    int row = P * 64 + (tid >> 2);
    int sa = mt * 128 + row;
    if (sa >= cnt) sa = cnt - 1;              // clamp (dup loads; masked at C-write)
    int gr = (MODE == 0) ? (pair_rows[off + sa] >> 1) : (off + sa);
    aptr[P] = Amat + (size_t)gr * Kd + csw;
    bptr[P] = Bex + (size_t)(n0 + row) * Kd + csw;
  }

  int wm = (wid >> 1) * 64, wn = (wid & 1) * 64;
  int lr = lane & 15;
  int t4 = lane >> 4;                         // k-chunk 0..3
  int lka = ((t4 ^ (lr & 3)) * 8);            // swizzled read element offset

  floatx4 acc[4][4];
#pragma unroll
  for (int m = 0; m < 4; ++m)
#pragma unroll
    for (int n = 0; n < 4; ++n) acc[m][n] = (floatx4){0.f, 0.f, 0.f, 0.f};

  int NT = Kd >> 5;
  // prologue: stage K-tiles 0 and 1 into ring slots 0,1 (dest linear: base + tid*16B)
#pragma unroll
  for (int P = 0; P < 2; ++P) {
    load_lds16(aptr[P], &As[0][P * 2048] + tid * 8);
    load_lds16(bptr[P], &Bs[0][P * 2048] + tid * 8);
  }
#pragma unroll
  for (int P = 0; P < 2; ++P) {
    load_lds16(aptr[P] + 32, &As[1][P * 2048] + tid * 8);
    load_lds16(bptr[P] + 32, &Bs[1][P * 2048] + tid * 8);
  }

  for (int kt = 0; kt < NT; ++kt) {
    if (kt + 1 < NT) {
      asm volatile("s_waitcnt vmcnt(4)" ::: "memory");  // tile kt landed; kt+1 in flight
    } else {
      asm volatile("s_waitcnt vmcnt(0)" ::: "memory");  // last tile: drain
    }
    __builtin_amdgcn_s_barrier();             // all waves finished iter kt-1 reads
    __builtin_amdgcn_sched_barrier(0);        // pin stage-issue after the barrier
    int pf = kt + 2;
    if (pf < NT) {                            // stage 2 ahead into slot (kt+2)%3=(kt-1)%3
      int ko = pf * 32;
      int pb = pf - (pf / 3) * 3;             // pf % 3
#pragma unroll
      for (int P = 0; P < 2; ++P) {
        load_lds16(aptr[P] + ko, &As[pb][P * 2048] + tid * 8);
        load_lds16(bptr[P] + ko, &Bs[pb][P * 2048] + tid * 8);
      }
    }
    int b = kt - (kt / 3) * 3;                // kt % 3
    bf16x8 af[4], bfr[4];
#pragma unroll
    for (int m = 0; m < 4; ++m)
      af[m] = *(const bf16x8*)(&As[b][(wm + m * 16 + lr) * 32 + lka]);
#pragma unroll
    for (int n = 0; n < 4; ++n)
      bfr[n] = *(const bf16x8*)(&Bs[b][(wn + n * 16 + lr) * 32 + lka]);
#pragma unroll
    for (int m = 0; m < 4; ++m)
#pragma unroll
      for (int n = 0; n < 4; ++n)
        acc[m][n] = __builtin_amdgcn_mfma_f32_16x16x32_bf16(af[m], bfr[n], acc[m][n], 0, 0, 0);
  }

  int rem = cnt - mt * 128;
  if (rem > 128) rem = 128;
#pragma unroll
  for (int m = 0; m < 4; ++m) {
#pragma unroll
    for (int j = 0; j < 4; ++j) {
      int lrr = wm + m * 16 + ((lane >> 4) << 2) + j;   // C/D: col=lane&15, row=(lane>>4)*4+j
      if (lrr < rem) {
        int s = mt * 128 + lrr;
        size_t orow;
        float scale = 1.f;
        if (MODE == 0) {
          orow = (size_t)(off + s) * Nd;
        } else {
          int p = pair_rows[off + s];
          orow = (size_t)p * Nd;
          scale = pair_w[p];
        }
#pragma unroll
        for (int n = 0; n < 4; ++n) {
          int col = n0 + wn + n * 16 + lr;
          float v = acc[m][n][j] + bias[e * Nd + col];
          if (MODE == 0) v = fmaxf(v, 0.f);
          else v *= scale;
          Out[orow + col] = f2bf(v);
        }
      }
    }
  }
}

// ---------------- fused epilogue: sum pairs, momentum, residual, LayerNorm ----------------
__global__ __launch_bounds__(256) void final_kernel(
    const float* __restrict__ x, const float* __restrict__ mom,
    const unsigned short* __restrict__ pairout, const float* __restrict__ ln_g,
    const float* __restrict__ ln_b, float* __restrict__ outp, float* __restrict__ nmp) {
  int t = blockIdx.x, tid = threadIdx.x;
  int d0 = tid * 4;
  size_t rowoff = (size_t)t * DD;
  const unsigned short* p0 = pairout + (size_t)(2 * t) * DD;
  const unsigned short* p1 = p0 + DD;
  float4 xv = *(const float4*)(x + rowoff + d0);
  float4 mv = *(const float4*)(mom + rowoff + d0);
  ushort4 u0 = *(const ushort4*)(p0 + d0);
  ushort4 u1 = *(const ushort4*)(p1 + d0);
  float eo[4] = {bf2f(u0.x) + bf2f(u1.x), bf2f(u0.y) + bf2f(u1.y),
                 bf2f(u0.z) + bf2f(u1.z), bf2f(u0.w) + bf2f(u1.w)};
  float xa[4] = {xv.x, xv.y, xv.z, xv.w};
  float ma[4] = {mv.x, mv.y, mv.z, mv.w};
  float o[4], nm[4];
  float s1 = 0.f, s2 = 0.f;
#pragma unroll
  for (int j = 0; j < 4; ++j) {
    nm[j] = MUf * ma[j] - eo[j];
    o[j] = xa[j] + GAMMAf * nm[j];
    s1 += o[j];
    s2 += o[j] * o[j];
  }
  *(float4*)(nmp + rowoff + d0) = make_float4(nm[0], nm[1], nm[2], nm[3]);
#pragma unroll
  for (int off = 32; off > 0; off >>= 1) {
    s1 += __shfl_xor(s1, off);
    s2 += __shfl_xor(s2, off);
  }
  __shared__ float rs[8];
  int wid = tid >> 6, lane = tid & 63;
  if (lane == 0) { rs[wid] = s1; rs[4 + wid] = s2; }
  __syncthreads();
  s1 = rs[0] + rs[1] + rs[2] + rs[3];
  s2 = rs[4] + rs[5] + rs[6] + rs[7];
  float mean = s1 * (1.f / DD);
  float var = s2 * (1.f / DD) - mean * mean;
  float rstd = rsqrtf(var + LNEPS);
  float4 g = *(const float4*)(ln_g + d0);
  float4 bb = *(const float4*)(ln_b + d0);
  float ga[4] = {g.x, g.y, g.z, g.w}, ba[4] = {bb.x, bb.y, bb.z, bb.w};
  float res[4];
#pragma unroll
  for (int j = 0; j < 4; ++j) res[j] = (o[j] - mean) * rstd * ga[j] + ba[j];
  *(float4*)(outp + rowoff + d0) = make_float4(res[0], res[1], res[2], res[3]);
}

extern "C" void kernel_launch(void* const* d_in, const int* in_sizes, int n_in,
                              void* d_out, int out_size, void* d_ws, size_t ws_size,
                              hipStream_t stream) {
  const float* x   = (const float*)d_in[0];
  const float* mom = (const float*)d_in[1];
  const float* Wg  = (const float*)d_in[2];
  const float* bg  = (const float*)d_in[3];
  const float* W1  = (const float*)d_in[4];
  const float* b1  = (const float*)d_in[5];
  const float* W2  = (const float*)d_in[6];
  const float* b2  = (const float*)d_in[7];
  const float* lng = (const float*)d_in[8];
  const float* lnb = (const float*)d_in[9];
  (void)in_sizes; (void)n_in; (void)out_size; (void)ws_size;
  float* outp = (float*)d_out;
  float* nmp  = outp + (size_t)TT * DD;

  char* base = (char*)d_ws;
  size_t off = 0;
  auto carve = [&](size_t bytes) {
    void* p = base + off;
    off += (bytes + 255) & ~(size_t)255;
    return p;
  };
  unsigned short* xb   = (unsigned short*)carve((size_t)TT * DD * 2);        // 16 MB
  unsigned short* w1t  = (unsigned short*)carve((size_t)EE * HHH * DD * 2);  // 32 MB  [E][H][D]
  unsigned short* w2t  = (unsigned short*)carve((size_t)EE * DD * HHH * 2);  // 32 MB  [E][D][H]
  unsigned short* hbuf = (unsigned short*)carve((size_t)2 * TT * HHH * 2);   // 64 MB
  unsigned short* pout = (unsigned short*)carve((size_t)2 * TT * DD * 2);    // 32 MB
  int*   pair_e    = (int*)carve((size_t)2 * TT * 4);
  float* pair_w    = (float*)carve((size_t)2 * TT * 4);
  int*   pair_rows = (int*)carve((size_t)2 * TT * 4);
  int*   counts    = (int*)carve(256);
  int*   offs      = (int*)carve(256);
  int*   cursor    = (int*)carve(256);

  hipMemsetAsync(counts, 0, EE * sizeof(int), stream);
  cvt_router_kernel<<<TT / 2, 256, 0, stream>>>(x, Wg, bg, xb, pair_e, pair_w);
  count_kernel<<<(2 * TT) / 256, 256, 0, stream>>>(pair_e, counts);
  prefix_kernel<<<1, 64, 0, stream>>>(counts, offs, cursor);
  scatter_kernel<<<(2 * TT) / 256, 256, 0, stream>>>(pair_e, cursor, pair_rows);
  transpose_cvt_kernel<<<dim3(HHH / 64, DD / 64, EE), 256, 0, stream>>>(W1, w1t, DD, HHH);
  transpose_cvt_kernel<<<dim3(DD / 64, HHH / 64, EE), 256, 0, stream>>>(W2, w2t, HHH, DD);
  // flat grids: 8 experts x (NX n-tiles x 128 m-tiles); expert = blockIdx.x & 7
  moe_gemm_kernel<0><<<EE * (HHH / 128) * 128, 256, 0, stream>>>(
      xb, w1t, b1, offs, pair_rows, pair_w, hbuf, DD, HHH, 4);
  moe_gemm_kernel<1><<<EE * (DD / 128) * 128, 256, 0, stream>>>(
      hbuf, w2t, b2, offs, pair_rows, pair_w, pout, HHH, DD, 3);
  final_kernel<<<TT, 256, 0, stream>>>(x, mom, pout, lng, lnb, outp, nmp);
}